// Round 15
// baseline (126.365 us; speedup 1.0000x reference)
//
#include <hip/hip_runtime.h>
#include <hip/hip_bf16.h>

typedef _Float16 f16;
typedef _Float16 f16x8 __attribute__((ext_vector_type(8)));
typedef _Float16 f16x4 __attribute__((ext_vector_type(4)));
typedef float f32x4 __attribute__((ext_vector_type(4)));
typedef int i32x4 __attribute__((ext_vector_type(4)));

#define LDS_LOAD16(gptr, lptr)                                                             \
  __builtin_amdgcn_global_load_lds(                                                        \
      (const __attribute__((address_space(1))) unsigned int*)(gptr),                       \
      (__attribute__((address_space(3))) unsigned int*)(lptr), 16, 0, 0)

// 0.125 (1/sqrt(HD)) * log2(e): folded into Q so QK^T yields log2e-scaled scores
#define ALPHA 0.18033688f
// masked score: reference sets score=1e-9 (log2e domain)
#define MASKVAL 1.44269504e-9f

// ---------------------------------------------------------------------------
// fused fp32 -> fp16 conversion for x + 4 weight matrices
// ---------------------------------------------------------------------------
__global__ __launch_bounds__(256) void conv_all(const float* __restrict__ x,
                                                const float* __restrict__ Wq,
                                                const float* __restrict__ Wk,
                                                const float* __restrict__ Wv,
                                                const float* __restrict__ Wo,
                                                f16* __restrict__ xh, f16* __restrict__ wqh,
                                                f16* __restrict__ wkh, f16* __restrict__ wvh,
                                                f16* __restrict__ woh) {
  int i = blockIdx.x * 256 + threadIdx.x;
  const float* src;
  f16* dst;
  int off;
  if (i < 524288) {
    src = x; dst = xh; off = i;
  } else {
    int j = i - 524288;
    int w = j >> 17;
    off = j & 131071;
    src = (w == 0) ? Wq : (w == 1) ? Wk : (w == 2) ? Wv : Wo;
    dst = (w == 0) ? wqh : (w == 1) ? wkh : (w == 2) ? wvh : woh;
  }
  const float4* s4 = (const float4*)src;
  float4 a = s4[2 * off];
  float4 b = s4[2 * off + 1];
  f16x8 o = {(f16)a.x, (f16)a.y, (f16)a.z, (f16)a.w,
             (f16)b.x, (f16)b.y, (f16)b.z, (f16)b.w};
  *(f16x8*)(dst + (size_t)off * 8) = o;
}

// ---------------------------------------------------------------------------
// Fused QKV projection: z=0 -> Q (scaled by ALPHA), z=1 -> K, z=2 -> V^T.
// 2-phase pipeline, counted vmcnt(4), dbuf LDS, XCD-chunked swizzle.
// z=2 epilogue: transpose the 128x128 tile through the (dead) staging LDS
// with XOR swizzle, then COALESCED f16x8 row stores into V^T -- replaces the
// old 8B/lane 4KB-stride scatter (~8x HBM write amplification).
// ---------------------------------------------------------------------------
__global__ __launch_bounds__(256) void gemm_qkv(const f16* __restrict__ A,
                                                const f16* __restrict__ W0,
                                                const f16* __restrict__ W1,
                                                const f16* __restrict__ W2,
                                                const float* __restrict__ b0,
                                                const float* __restrict__ b1,
                                                const float* __restrict__ b2,
                                                f16* __restrict__ qo, f16* __restrict__ ko,
                                                f16* __restrict__ vo) {
  constexpr int K = 1024, BM = 128, BK = 32, NKT = K / BK;
  // [ aT: 2x8KB | bT: 2x8KB ] = 32 KB; reused as transpose scratch for z=2
  __shared__ __align__(16) f16 smem[16384];
  const int rid = (blockIdx.x & 7) * 96 + (blockIdx.x >> 3);
  const int z = rid >> 8;
  const f16* Bw = (z == 0) ? W0 : (z == 1) ? W1 : W2;
  const float* bias = (z == 0) ? b0 : (z == 1) ? b1 : b2;
  const int tid = threadIdx.x, wid = tid >> 6, lane = tid & 63;
  const int mb = ((rid >> 3) & 31) * BM, nb = (rid & 7) * BM;
  const int wr = wid >> 1, wc = wid & 1;
  const int lr = lane & 15, hi = lane >> 4;

  f32x4 acc[4][4] = {};

  const int r0 = tid >> 2, s0 = tid & 3;
  const int ci1 = 256 + tid, r1 = ci1 >> 2, s1 = ci1 & 3;

#define STAGE_QKV(bb, kt)                                                                   \
  do {                                                                                      \
    const int kb_ = (kt) * BK;                                                              \
    LDS_LOAD16(A + (size_t)(mb + r0) * K + kb_ + s0 * 8, (char*)smem + (bb) * 8192 + wid * 1024); \
    LDS_LOAD16(Bw + (size_t)(nb + r0) * K + kb_ + s0 * 8,                                   \
               (char*)smem + 16384 + (bb) * 8192 + wid * 1024);                             \
    LDS_LOAD16(A + (size_t)(mb + r1) * K + kb_ + s1 * 8,                                    \
               (char*)smem + (bb) * 8192 + 4096 + wid * 1024);                              \
    LDS_LOAD16(Bw + (size_t)(nb + r1) * K + kb_ + s1 * 8,                                   \
               (char*)smem + 16384 + (bb) * 8192 + 4096 + wid * 1024);                      \
  } while (0)

  STAGE_QKV(0, 0);
  for (int kt = 0; kt < NKT; ++kt) {
    const int p = kt & 1;
    if (kt + 1 < NKT) {
      STAGE_QKV(p ^ 1, kt + 1);
      asm volatile("s_waitcnt vmcnt(4)" ::: "memory");
    } else {
      asm volatile("s_waitcnt vmcnt(0)" ::: "memory");
    }
    __builtin_amdgcn_s_barrier();

    const f16* aTp = smem + p * 4096;
    const f16* bTp = smem + 8192 + p * 4096;
    f16x8 af[4], bf[4];
#pragma unroll
    for (int i = 0; i < 4; ++i) af[i] = *(const f16x8*)&aTp[(wr * 64 + i * 16 + lr) * BK + hi * 8];
#pragma unroll
    for (int j = 0; j < 4; ++j) bf[j] = *(const f16x8*)&bTp[(wc * 64 + j * 16 + lr) * BK + hi * 8];
    __builtin_amdgcn_s_setprio(1);
#pragma unroll
    for (int i = 0; i < 4; ++i)
#pragma unroll
      for (int j = 0; j < 4; ++j)
        acc[i][j] = __builtin_amdgcn_mfma_f32_16x16x32_f16(af[i], bf[j], acc[i][j], 0, 0, 0);
    __builtin_amdgcn_s_setprio(0);
    __builtin_amdgcn_s_barrier();
  }

  if (z == 2) {
    // ---- transpose through LDS, then coalesced V^T stores ----
    __syncthreads();
#pragma unroll
    for (int i = 0; i < 4; ++i) {
#pragma unroll
      for (int j = 0; j < 4; ++j) {
        const int colL = wc * 64 + j * 16 + lr;   // local d
        const int rowL = wr * 64 + i * 16 + hi * 4;  // local l
        const float bv = bias[nb + colL];
        f16x4 v4;
#pragma unroll
        for (int r = 0; r < 4; ++r) v4[r] = (f16)(acc[i][j][r] + bv);
        int byte = colL * 256 + rowL * 2;
        byte ^= (colL & 7) << 4;
        *(f16x4*)((char*)smem + byte) = v4;
      }
    }
    __syncthreads();
    const int dl = tid >> 1, hf = tid & 1;
    const int col = nb + dl;
    const int hh = col >> 6, dd = col & 63;
    const int bb = mb >> 11, l0 = mb & 2047;
    f16* vop = vo + (((size_t)bb * 16 + hh) * 64 + dd) * 2048 + l0 + hf * 64;
#pragma unroll
    for (int c = 0; c < 8; ++c) {
      int byte = dl * 256 + hf * 128 + c * 16;
      byte ^= (dl & 7) << 4;
      *(f16x8*)&vop[c * 8] = *(const f16x8*)((char*)smem + byte);
    }
  } else {
    const float scale = (z == 0) ? ALPHA : 1.0f;
#pragma unroll
    for (int i = 0; i < 4; ++i) {
#pragma unroll
      for (int j = 0; j < 4; ++j) {
        const int row = mb + wr * 64 + i * 16 + hi * 4;
        const int col = nb + wc * 64 + j * 16 + lr;
        const float bv = bias[col];
        const int hh = col >> 6, dd = col & 63;
        f16* o = z ? ko : qo;
#pragma unroll
        for (int r = 0; r < 4; ++r) {
          const int m2 = row + r;
          const int bb = m2 >> 11, l = m2 & 2047;
          o[((((size_t)bb * 16 + hh) * 2048 + l) * 64) + dd] = (f16)((acc[i][j][r] + bv) * scale);
        }
      }
    }
  }
}

// ---------------------------------------------------------------------------
// Output projection: 64(M)x128(N) tile, 2-phase pipeline, XCD-chunked swizzle.
// ---------------------------------------------------------------------------
__global__ __launch_bounds__(256) void gemm_o(const f16* __restrict__ A,
                                              const f16* __restrict__ W,
                                              const float* __restrict__ bias,
                                              float* __restrict__ out) {
  constexpr int K = 1024, N = 1024, BK = 32, NKT = K / BK;
  __shared__ f16 aT[2][64 * BK];
  __shared__ f16 bT[2][128 * BK];
  const int rid = (blockIdx.x & 7) * 64 + (blockIdx.x >> 3);
  const int tid = threadIdx.x, wid = tid >> 6, lane = tid & 63;
  const int lr = lane & 15, hi = lane >> 4;
  const int mb = (rid >> 3) * 64, nb = (rid & 7) * 128;
  const int wr = wid >> 1, wc = wid & 1;
  f32x4 acc[2][4] = {};
  const int ra = tid >> 2, sa = tid & 3;
  const int rb1 = (256 + tid) >> 2, sb1 = (256 + tid) & 3;

#define STAGE_O(bb, kt)                                                                     \
  do {                                                                                      \
    const int kb_ = (kt) * BK;                                                              \
    LDS_LOAD16(A + (size_t)(mb + ra) * K + kb_ + sa * 8, (char*)aT[bb] + wid * 1024);       \
    LDS_LOAD16(W + (size_t)(nb + ra) * K + kb_ + sa * 8, (char*)bT[bb] + wid * 1024);       \
    LDS_LOAD16(W + (size_t)(nb + rb1) * K + kb_ + sb1 * 8, (char*)bT[bb] + 4096 + wid * 1024);\
  } while (0)

  STAGE_O(0, 0);
  for (int kt = 0; kt < NKT; ++kt) {
    const int p = kt & 1;
    if (kt + 1 < NKT) {
      STAGE_O(p ^ 1, kt + 1);
      asm volatile("s_waitcnt vmcnt(3)" ::: "memory");
    } else {
      asm volatile("s_waitcnt vmcnt(0)" ::: "memory");
    }
    __builtin_amdgcn_s_barrier();
    f16x8 af[2], bf[4];
#pragma unroll
    for (int i = 0; i < 2; ++i) af[i] = *(const f16x8*)&aT[p][(wr * 32 + i * 16 + lr) * BK + hi * 8];
#pragma unroll
    for (int j = 0; j < 4; ++j) bf[j] = *(const f16x8*)&bT[p][(wc * 64 + j * 16 + lr) * BK + hi * 8];
    __builtin_amdgcn_s_setprio(1);
#pragma unroll
    for (int i = 0; i < 2; ++i)
#pragma unroll
      for (int j = 0; j < 4; ++j)
        acc[i][j] = __builtin_amdgcn_mfma_f32_16x16x32_f16(af[i], bf[j], acc[i][j], 0, 0, 0);
    __builtin_amdgcn_s_setprio(0);
    __builtin_amdgcn_s_barrier();
  }
#pragma unroll
  for (int i = 0; i < 2; ++i)
#pragma unroll
    for (int j = 0; j < 4; ++j) {
      const int col = nb + wc * 64 + j * 16 + lr;
      const float bv = bias[col];
#pragma unroll
      for (int r = 0; r < 4; ++r)
        out[(size_t)(mb + wr * 32 + i * 16 + hi * 4 + r) * N + col] = acc[i][j][r] + bv;
    }
}

// ---------------------------------------------------------------------------
// Flash attention v8 (kv-split hybrid), unchanged from r14 (54.6 us).
// ---------------------------------------------------------------------------
__global__ __launch_bounds__(256, 4) void attn4w(const f16* __restrict__ Qh,
                                                 const f16* __restrict__ Kh,
                                                 const f16* __restrict__ Vt,
                                                 const int* __restrict__ mask,
                                                 f16* __restrict__ Oa) {
  constexpr int L = 2048, HD = 64, H = 16, NT = L / 64;
  __shared__ __align__(16) char ldsb[32768];

  const int tid = threadIdx.x, wid = tid >> 6, lane = tid & 63;
  const int wk = wid >> 1, wq = wid & 1;
  const int lr = lane & 15, hi = lane >> 4;
  const int sw = lr & 7;

  const int bid = blockIdx.x;  // 1024 blocks
  const int head = (bid & 7) * 4 + (bid >> 8);
  const int qb = (bid >> 3) & 31;
  const int b = head >> 4, h = head & 15;
  const int qr0 = qb * 64 + wq * 32;

  const f16* Qb = Qh + (size_t)head * L * HD;
  const f16* Kb = Kh + (size_t)head * L * HD;
  const f16* Vb = Vt + (size_t)head * HD * L;
  const int* mrow = mask + b * L;

  int mred = 1;
  {
    const int4* m4 = (const int4*)mrow;
#pragma unroll
    for (int j = 0; j < 8; ++j) {
      int4 v = m4[lane + j * 64];
      mred &= v.x & v.y & v.z & v.w;
    }
  }
  const bool allm = __all(mred == 1);

  const int srow = lane >> 3;
  const int schk = (lane & 7) ^ srow;

#define STAGE_KV(bb, kt)                                                                    \
  _Pragma("unroll") for (int c = 0; c < 2; ++c) {                                           \
    LDS_LOAD16(Kb + (size_t)((kt) * 64 + wid * 16 + c * 8 + srow) * HD + schk * 8,          \
               ldsb + (bb) * 16384 + wid * 2048 + c * 1024);                                \
    LDS_LOAD16(Vb + (size_t)(wid * 16 + c * 8 + srow) * L + (kt) * 64 + schk * 8,           \
               ldsb + (bb) * 16384 + 8192 + wid * 2048 + c * 1024);                         \
  }

  const char* kbase0 = ldsb + (wk * 32 + lr) * 128 + ((hi ^ sw) * 16);
  const char* kbase1 = ldsb + (wk * 32 + lr) * 128 + (((4 + hi) ^ sw) * 16);
  const char* vbase = ldsb + 8192 + lr * 128 + (((wk * 4 + hi) ^ sw) * 16);

  f16x8 qf[2][2];
#pragma unroll
  for (int qg = 0; qg < 2; ++qg)
#pragma unroll
    for (int k2 = 0; k2 < 2; ++k2)
      qf[qg][k2] = *(const f16x8*)&Qb[(size_t)(qr0 + qg * 16 + lr) * HD + k2 * 32 + hi * 8];

  f32x4 oacc[2][4] = {};
  f32x4 lacc[2] = {};
  const f32x4 zacc = {0.f, 0.f, 0.f, 0.f};
  const f16x8 ones = {1, 1, 1, 1, 1, 1, 1, 1};

  int4 mvA[2], mvB[2];
  if (!allm) {
#pragma unroll
    for (int kvg = 0; kvg < 2; ++kvg)
      mvA[kvg] = *(const int4*)&mrow[wk * 32 + kvg * 16 + hi * 4];
  }
  STAGE_KV(0, 0);

#define ATTN_ITER(kt, P, MVR, MVL)                                                          \
  do {                                                                                      \
    asm volatile("s_waitcnt vmcnt(0)" ::: "memory");                                        \
    __builtin_amdgcn_s_barrier();                                                           \
    if ((kt) + 1 < NT) {                                                                    \
      if (!allm) {                                                                          \
        _Pragma("unroll") for (int kvg = 0; kvg < 2; ++kvg)                                 \
            MVL[kvg] = *(const int4*)&mrow[((kt) + 1) * 64 + wk * 32 + kvg * 16 + hi * 4];  \
      }                                                                                     \
      STAGE_KV((P) ^ 1, (kt) + 1);                                                          \
    }                                                                                       \
    f16x8 kf[2][2];                                                                         \
    _Pragma("unroll") for (int kvg = 0; kvg < 2; ++kvg) {                                   \
      kf[kvg][0] = *(const f16x8*)(kbase0 + (P) * 16384 + kvg * 2048);                      \
      kf[kvg][1] = *(const f16x8*)(kbase1 + (P) * 16384 + kvg * 2048);                      \
    }                                                                                       \
    f32x4 s[2][2];                                                                          \
    __builtin_amdgcn_s_setprio(1);                                                          \
    _Pragma("unroll") for (int qg = 0; qg < 2; ++qg)                                        \
        _Pragma("unroll") for (int kvg = 0; kvg < 2; ++kvg) {                               \
      f32x4 z = __builtin_amdgcn_mfma_f32_16x16x32_f16(kf[kvg][0], qf[qg][0], zacc, 0, 0, 0);\
      s[qg][kvg] = __builtin_amdgcn_mfma_f32_16x16x32_f16(kf[kvg][1], qf[qg][1], z, 0, 0, 0);\
    }                                                                                       \
    __builtin_amdgcn_s_setprio(0);                                                          \
    f16x8 pf[2];                                                                            \
    _Pragma("unroll") for (int qg = 0; qg < 2; ++qg) {                                      \
      int wpk[2][2];                                                                        \
      _Pragma("unroll") for (int kvg = 0; kvg < 2; ++kvg) {                                 \
        float p0, p1, p2, p3;                                                               \
        if (allm) {                                                                         \
          p0 = __builtin_amdgcn_exp2f(s[qg][kvg][0]);                                       \
          p1 = __builtin_amdgcn_exp2f(s[qg][kvg][1]);                                       \
          p2 = __builtin_amdgcn_exp2f(s[qg][kvg][2]);                                       \
          p3 = __builtin_amdgcn_exp2f(s[qg][kvg][3]);                                       \
        } else {                                                                            \
          p0 = __builtin_amdgcn_exp2f(MVR[kvg].x ? s[qg][kvg][0] : MASKVAL);                \
          p1 = __builtin_amdgcn_exp2f(MVR[kvg].y ? s[qg][kvg][1] : MASKVAL);                \
          p2 = __builtin_amdgcn_exp2f(MVR[kvg].z ? s[qg][kvg][2] : MASKVAL);                \
          p3 = __builtin_amdgcn_exp2f(MVR[kvg].w ? s[qg][kvg][3] : MASKVAL);                \
        }                                                                                   \
        wpk[kvg][0] = __builtin_bit_cast(int, __builtin_amdgcn_cvt_pkrtz(p0, p1));          \
        wpk[kvg][1] = __builtin_bit_cast(int, __builtin_amdgcn_cvt_pkrtz(p2, p3));          \
      }                                                                                     \
      int A0 = wpk[0][0], B0 = wpk[1][0];                                                   \
      int A1 = wpk[0][1], B1 = wpk[1][1];                                                   \
      asm("v_permlane32_swap_b32 %0, %1" : "+v"(A0), "+v"(B0));                             \
      asm("v_permlane16_swap_b32 %0, %1" : "+v"(A0), "+v"(B0));                             \
      asm("v_permlane32_swap_b32 %0, %1" : "+v"(A1), "+v"(B1));                             \
      asm("v_permlane16_swap_b32 %0, %1" : "+v"(A1), "+v"(B1));                             \
      i32x4 cc = {A0, A1, B0, B1};                                                          \
      pf[qg] = __builtin_bit_cast(f16x8, cc);                                               \
    }                                                                                       \
    f16x8 vf[4];                                                                            \
    _Pragma("unroll") for (int df = 0; df < 4; ++df)                                        \
        vf[df] = *(const f16x8*)(vbase + (P) * 16384 + df * 2048);                          \
    __builtin_amdgcn_s_setprio(1);                                                          \
    _Pragma("unroll") for (int qg = 0; qg < 2; ++qg) {                                      \
      _Pragma("unroll") for (int df = 0; df < 4; ++df)                                      \
          oacc[qg][df] = __builtin_amdgcn_mfma_f32_16x16x32_f16(pf[qg], vf[df], oacc[qg][df], 0, 0, 0); \
      lacc[qg] = __builtin_amdgcn_mfma_f32_16x16x32_f16(pf[qg], ones, lacc[qg], 0, 0, 0);   \
    }                                                                                       \
    __builtin_amdgcn_s_setprio(0);                                                          \
  } while (0)

  for (int kt = 0; kt < NT; kt += 2) {
    ATTN_ITER(kt, 0, mvA, mvB);
    ATTN_ITER(kt + 1, 1, mvB, mvA);
  }

  // ---- cross-wave (wk) reduction through the dead staging LDS ----
  __syncthreads();
  if (wk == 1) {
#pragma unroll
    for (int qg = 0; qg < 2; ++qg) {
#pragma unroll
      for (int df = 0; df < 4; ++df)
        *(f32x4*)(ldsb + wq * 8192 + (qg * 4 + df) * 1024 + lane * 16) = oacc[qg][df];
      *(f32x4*)(ldsb + 16384 + (wq * 2 + qg) * 1024 + lane * 16) = lacc[qg];
    }
  }
  __syncthreads();
  if (wk == 0) {
#pragma unroll
    for (int qg = 0; qg < 2; ++qg) {
#pragma unroll
      for (int df = 0; df < 4; ++df)
        oacc[qg][df] += *(const f32x4*)(ldsb + wq * 8192 + (qg * 4 + df) * 1024 + lane * 16);
      lacc[qg] += *(const f32x4*)(ldsb + 16384 + (wq * 2 + qg) * 1024 + lane * 16);
    }
#pragma unroll
    for (int qg = 0; qg < 2; ++qg) {
      f32x4 rinv;
#pragma unroll
      for (int r = 0; r < 4; ++r) rinv[r] = 1.0f / lacc[qg][r];
#pragma unroll
      for (int df = 0; df < 4; ++df)
#pragma unroll
        for (int r = 0; r < 4; ++r) {
          const int l = qr0 + qg * 16 + hi * 4 + r;
          Oa[(((size_t)b * L + l) * H + h) * HD + df * 16 + lr] =
              (f16)(oacc[qg][df][r] * rinv[r]);
        }
    }
  }
}

// ---------------------------------------------------------------------------
extern "C" void kernel_launch(void* const* d_in, const int* in_sizes, int n_in,
                              void* d_out, int out_size, void* d_ws, size_t ws_size,
                              hipStream_t stream) {
  const float* x  = (const float*)d_in[0];
  const int* mask = (const int*)d_in[1];
  const float* Wq = (const float*)d_in[2];
  const float* bq = (const float*)d_in[3];
  const float* Wk = (const float*)d_in[4];
  const float* bk = (const float*)d_in[5];
  const float* Wv = (const float*)d_in[6];
  const float* bv = (const float*)d_in[7];
  const float* Wo = (const float*)d_in[8];
  const float* bo = (const float*)d_in[9];
  float* out = (float*)d_out;

  char* ws = (char*)d_ws;
  const size_t MB = 1u << 20;
  f16* xh  = (f16*)(ws);             // 4096x1024  (8 MB)
  f16* wqh = (f16*)(ws + 8 * MB);    // 1024x1024  (2 MB)
  f16* wkh = (f16*)(ws + 10 * MB);
  f16* wvh = (f16*)(ws + 12 * MB);
  f16* woh = (f16*)(ws + 14 * MB);
  f16* qh  = (f16*)(ws + 16 * MB);   // [2][16][2048][64], pre-scaled by ALPHA
  f16* kh  = (f16*)(ws + 24 * MB);   // [2][16][2048][64]
  f16* vth = (f16*)(ws + 32 * MB);   // [2][16][64][2048]
  f16* oah = (f16*)(ws + 40 * MB);   // [2][2048][16][64] = [4096][1024]

  conv_all<<<4096, 256, 0, stream>>>(x, Wq, Wk, Wv, Wo, xh, wqh, wkh, wvh, woh);

  gemm_qkv<<<768, 256, 0, stream>>>(xh, wqh, wkh, wvh, bq, bk, bv, qh, kh, vth);

  attn4w<<<dim3(1024), 256, 0, stream>>>(qh, kh, vth, mask, oah);

  gemm_o<<<512, 256, 0, stream>>>(oah, woh, bo, out);
}

// Round 16
// 117.077 us; speedup vs baseline: 1.0793x; 1.0793x over previous
//
#include <hip/hip_runtime.h>
#include <hip/hip_bf16.h>

typedef _Float16 f16;
typedef _Float16 f16x8 __attribute__((ext_vector_type(8)));
typedef _Float16 f16x4 __attribute__((ext_vector_type(4)));
typedef float f32x4 __attribute__((ext_vector_type(4)));
typedef int i32x4 __attribute__((ext_vector_type(4)));

#define LDS_LOAD16(gptr, lptr)                                                             \
  __builtin_amdgcn_global_load_lds(                                                        \
      (const __attribute__((address_space(1))) unsigned int*)(gptr),                       \
      (__attribute__((address_space(3))) unsigned int*)(lptr), 16, 0, 0)

// 0.125 (1/sqrt(HD)) * log2(e): folded into Q so QK^T yields log2e-scaled scores
#define ALPHA 0.18033688f
// masked score: reference sets score=1e-9 (log2e domain)
#define MASKVAL 1.44269504e-9f

// ---------------------------------------------------------------------------
// fused fp32 -> fp16 conversion for x + 4 weight matrices
// ---------------------------------------------------------------------------
__global__ __launch_bounds__(256) void conv_all(const float* __restrict__ x,
                                                const float* __restrict__ Wq,
                                                const float* __restrict__ Wk,
                                                const float* __restrict__ Wv,
                                                const float* __restrict__ Wo,
                                                f16* __restrict__ xh, f16* __restrict__ wqh,
                                                f16* __restrict__ wkh, f16* __restrict__ wvh,
                                                f16* __restrict__ woh) {
  int i = blockIdx.x * 256 + threadIdx.x;
  const float* src;
  f16* dst;
  int off;
  if (i < 524288) {
    src = x; dst = xh; off = i;
  } else {
    int j = i - 524288;
    int w = j >> 17;
    off = j & 131071;
    src = (w == 0) ? Wq : (w == 1) ? Wk : (w == 2) ? Wv : Wo;
    dst = (w == 0) ? wqh : (w == 1) ? wkh : (w == 2) ? wvh : woh;
  }
  const float4* s4 = (const float4*)src;
  float4 a = s4[2 * off];
  float4 b = s4[2 * off + 1];
  f16x8 o = {(f16)a.x, (f16)a.y, (f16)a.z, (f16)a.w,
             (f16)b.x, (f16)b.y, (f16)b.z, (f16)b.w};
  *(f16x8*)(dst + (size_t)off * 8) = o;
}

// ---------------------------------------------------------------------------
// Fused QKV projection: z=0 -> Q (scaled by ALPHA), z=1 -> K, z=2 -> V^T.
// 2-phase pipeline, counted vmcnt(4), dbuf LDS, XCD-chunked swizzle.
// ---------------------------------------------------------------------------
__global__ __launch_bounds__(256) void gemm_qkv(const f16* __restrict__ A,
                                                const f16* __restrict__ W0,
                                                const f16* __restrict__ W1,
                                                const f16* __restrict__ W2,
                                                const float* __restrict__ b0,
                                                const float* __restrict__ b1,
                                                const float* __restrict__ b2,
                                                f16* __restrict__ qo, f16* __restrict__ ko,
                                                f16* __restrict__ vo) {
  constexpr int K = 1024, BM = 128, BK = 32, NKT = K / BK;
  __shared__ f16 aT[2][BM * BK];
  __shared__ f16 bT[2][BM * BK];
  const int rid = (blockIdx.x & 7) * 96 + (blockIdx.x >> 3);
  const int z = rid >> 8;
  const f16* Bw = (z == 0) ? W0 : (z == 1) ? W1 : W2;
  const float* bias = (z == 0) ? b0 : (z == 1) ? b1 : b2;
  const int tid = threadIdx.x, wid = tid >> 6, lane = tid & 63;
  const int mb = ((rid >> 3) & 31) * BM, nb = (rid & 7) * BM;
  const int wr = wid >> 1, wc = wid & 1;
  const int lr = lane & 15, hi = lane >> 4;

  f32x4 acc[4][4] = {};

  const int r0 = tid >> 2, s0 = tid & 3;
  const int ci1 = 256 + tid, r1 = ci1 >> 2, s1 = ci1 & 3;

#define STAGE_QKV(bb, kt)                                                                   \
  do {                                                                                      \
    const int kb_ = (kt) * BK;                                                              \
    LDS_LOAD16(A + (size_t)(mb + r0) * K + kb_ + s0 * 8, (char*)aT[bb] + wid * 1024);       \
    LDS_LOAD16(Bw + (size_t)(nb + r0) * K + kb_ + s0 * 8, (char*)bT[bb] + wid * 1024);      \
    LDS_LOAD16(A + (size_t)(mb + r1) * K + kb_ + s1 * 8, (char*)aT[bb] + 4096 + wid * 1024);\
    LDS_LOAD16(Bw + (size_t)(nb + r1) * K + kb_ + s1 * 8, (char*)bT[bb] + 4096 + wid * 1024);\
  } while (0)

  STAGE_QKV(0, 0);
  for (int kt = 0; kt < NKT; ++kt) {
    const int p = kt & 1;
    if (kt + 1 < NKT) {
      STAGE_QKV(p ^ 1, kt + 1);
      asm volatile("s_waitcnt vmcnt(4)" ::: "memory");
    } else {
      asm volatile("s_waitcnt vmcnt(0)" ::: "memory");
    }
    __builtin_amdgcn_s_barrier();

    f16x8 af[4], bf[4];
#pragma unroll
    for (int i = 0; i < 4; ++i) af[i] = *(const f16x8*)&aT[p][(wr * 64 + i * 16 + lr) * BK + hi * 8];
#pragma unroll
    for (int j = 0; j < 4; ++j) bf[j] = *(const f16x8*)&bT[p][(wc * 64 + j * 16 + lr) * BK + hi * 8];
    __builtin_amdgcn_s_setprio(1);
#pragma unroll
    for (int i = 0; i < 4; ++i)
#pragma unroll
      for (int j = 0; j < 4; ++j)
        acc[i][j] = __builtin_amdgcn_mfma_f32_16x16x32_f16(af[i], bf[j], acc[i][j], 0, 0, 0);
    __builtin_amdgcn_s_setprio(0);
    __builtin_amdgcn_s_barrier();
  }

  const float scale = (z == 0) ? ALPHA : 1.0f;
#pragma unroll
  for (int i = 0; i < 4; ++i) {
#pragma unroll
    for (int j = 0; j < 4; ++j) {
      const int row = mb + wr * 64 + i * 16 + hi * 4;
      const int col = nb + wc * 64 + j * 16 + lr;
      const float bv = bias[col];
      const int hh = col >> 6, dd = col & 63;
      if (z == 2) {
        const int bb = row >> 11, l = row & 2047;
        f16x4 v4;
#pragma unroll
        for (int r = 0; r < 4; ++r) v4[r] = (f16)(acc[i][j][r] + bv);
        *(f16x4*)(vo + ((((size_t)bb * 16 + hh) * 64 + dd) * 2048 + l)) = v4;
      } else {
        f16* o = z ? ko : qo;
#pragma unroll
        for (int r = 0; r < 4; ++r) {
          const int m2 = row + r;
          const int bb = m2 >> 11, l = m2 & 2047;
          o[((((size_t)bb * 16 + hh) * 2048 + l) * 64) + dd] = (f16)((acc[i][j][r] + bv) * scale);
        }
      }
    }
  }
}

// ---------------------------------------------------------------------------
// Output projection: 64(M)x128(N) tile, 2-phase pipeline, XCD-chunked swizzle.
// ---------------------------------------------------------------------------
__global__ __launch_bounds__(256) void gemm_o(const f16* __restrict__ A,
                                              const f16* __restrict__ W,
                                              const float* __restrict__ bias,
                                              float* __restrict__ out) {
  constexpr int K = 1024, N = 1024, BK = 32, NKT = K / BK;
  __shared__ f16 aT[2][64 * BK];
  __shared__ f16 bT[2][128 * BK];
  const int rid = (blockIdx.x & 7) * 64 + (blockIdx.x >> 3);
  const int tid = threadIdx.x, wid = tid >> 6, lane = tid & 63;
  const int lr = lane & 15, hi = lane >> 4;
  const int mb = (rid >> 3) * 64, nb = (rid & 7) * 128;
  const int wr = wid >> 1, wc = wid & 1;
  f32x4 acc[2][4] = {};
  const int ra = tid >> 2, sa = tid & 3;
  const int rb1 = (256 + tid) >> 2, sb1 = (256 + tid) & 3;

#define STAGE_O(bb, kt)                                                                     \
  do {                                                                                      \
    const int kb_ = (kt) * BK;                                                              \
    LDS_LOAD16(A + (size_t)(mb + ra) * K + kb_ + sa * 8, (char*)aT[bb] + wid * 1024);       \
    LDS_LOAD16(W + (size_t)(nb + ra) * K + kb_ + sa * 8, (char*)bT[bb] + wid * 1024);       \
    LDS_LOAD16(W + (size_t)(nb + rb1) * K + kb_ + sb1 * 8, (char*)bT[bb] + 4096 + wid * 1024);\
  } while (0)

  STAGE_O(0, 0);
  for (int kt = 0; kt < NKT; ++kt) {
    const int p = kt & 1;
    if (kt + 1 < NKT) {
      STAGE_O(p ^ 1, kt + 1);
      asm volatile("s_waitcnt vmcnt(3)" ::: "memory");
    } else {
      asm volatile("s_waitcnt vmcnt(0)" ::: "memory");
    }
    __builtin_amdgcn_s_barrier();
    f16x8 af[2], bf[4];
#pragma unroll
    for (int i = 0; i < 2; ++i) af[i] = *(const f16x8*)&aT[p][(wr * 32 + i * 16 + lr) * BK + hi * 8];
#pragma unroll
    for (int j = 0; j < 4; ++j) bf[j] = *(const f16x8*)&bT[p][(wc * 64 + j * 16 + lr) * BK + hi * 8];
    __builtin_amdgcn_s_setprio(1);
#pragma unroll
    for (int i = 0; i < 2; ++i)
#pragma unroll
      for (int j = 0; j < 4; ++j)
        acc[i][j] = __builtin_amdgcn_mfma_f32_16x16x32_f16(af[i], bf[j], acc[i][j], 0, 0, 0);
    __builtin_amdgcn_s_setprio(0);
    __builtin_amdgcn_s_barrier();
  }
#pragma unroll
  for (int i = 0; i < 2; ++i)
#pragma unroll
    for (int j = 0; j < 4; ++j) {
      const int col = nb + wc * 64 + j * 16 + lr;
      const float bv = bias[col];
#pragma unroll
      for (int r = 0; r < 4; ++r)
        out[(size_t)(mb + wr * 32 + i * 16 + hi * 4 + r) * N + col] = acc[i][j][r] + bv;
    }
}

// ---------------------------------------------------------------------------
// Flash attention v8 (kv-split hybrid): 4 waves = 2(kv-half) x 2(q-half).
// Wave (wk,wq) computes PARTIAL O for q rows [wq*32,wq*32+32) over kv slice
// [wk*32,wk*32+32) of each 64-KV tile; partial O/lsum reduced once at end
// through the dead staging LDS.  dbuf staging, 1 barrier/tile, in-register
// P transpose (permlane32+16), ones-MFMA row-sums, mask all-ones fast path,
// p = exp2(score*log2e) (Q pre-scaled by ALPHA).
// ---------------------------------------------------------------------------
__global__ __launch_bounds__(256, 4) void attn4w(const f16* __restrict__ Qh,
                                                 const f16* __restrict__ Kh,
                                                 const f16* __restrict__ Vt,
                                                 const int* __restrict__ mask,
                                                 f16* __restrict__ Oa) {
  constexpr int L = 2048, HD = 64, H = 16, NT = L / 64;
  __shared__ __align__(16) char ldsb[32768];

  const int tid = threadIdx.x, wid = tid >> 6, lane = tid & 63;
  const int wk = wid >> 1, wq = wid & 1;
  const int lr = lane & 15, hi = lane >> 4;
  const int sw = lr & 7;

  const int bid = blockIdx.x;  // 1024 blocks
  const int head = (bid & 7) * 4 + (bid >> 8);
  const int qb = (bid >> 3) & 31;
  const int b = head >> 4, h = head & 15;
  const int qr0 = qb * 64 + wq * 32;

  const f16* Qb = Qh + (size_t)head * L * HD;
  const f16* Kb = Kh + (size_t)head * L * HD;
  const f16* Vb = Vt + (size_t)head * HD * L;
  const int* mrow = mask + b * L;

  int mred = 1;
  {
    const int4* m4 = (const int4*)mrow;
#pragma unroll
    for (int j = 0; j < 8; ++j) {
      int4 v = m4[lane + j * 64];
      mred &= v.x & v.y & v.z & v.w;
    }
  }
  const bool allm = __all(mred == 1);

  const int srow = lane >> 3;
  const int schk = (lane & 7) ^ srow;

#define STAGE_KV(bb, kt)                                                                    \
  _Pragma("unroll") for (int c = 0; c < 2; ++c) {                                           \
    LDS_LOAD16(Kb + (size_t)((kt) * 64 + wid * 16 + c * 8 + srow) * HD + schk * 8,          \
               ldsb + (bb) * 16384 + wid * 2048 + c * 1024);                                \
    LDS_LOAD16(Vb + (size_t)(wid * 16 + c * 8 + srow) * L + (kt) * 64 + schk * 8,           \
               ldsb + (bb) * 16384 + 8192 + wid * 2048 + c * 1024);                         \
  }

  const char* kbase0 = ldsb + (wk * 32 + lr) * 128 + ((hi ^ sw) * 16);
  const char* kbase1 = ldsb + (wk * 32 + lr) * 128 + (((4 + hi) ^ sw) * 16);
  const char* vbase = ldsb + 8192 + lr * 128 + (((wk * 4 + hi) ^ sw) * 16);

  f16x8 qf[2][2];
#pragma unroll
  for (int qg = 0; qg < 2; ++qg)
#pragma unroll
    for (int k2 = 0; k2 < 2; ++k2)
      qf[qg][k2] = *(const f16x8*)&Qb[(size_t)(qr0 + qg * 16 + lr) * HD + k2 * 32 + hi * 8];

  f32x4 oacc[2][4] = {};
  f32x4 lacc[2] = {};
  const f32x4 zacc = {0.f, 0.f, 0.f, 0.f};
  const f16x8 ones = {1, 1, 1, 1, 1, 1, 1, 1};

  int4 mvA[2], mvB[2];
  if (!allm) {
#pragma unroll
    for (int kvg = 0; kvg < 2; ++kvg)
      mvA[kvg] = *(const int4*)&mrow[wk * 32 + kvg * 16 + hi * 4];
  }
  STAGE_KV(0, 0);

#define ATTN_ITER(kt, P, MVR, MVL)                                                          \
  do {                                                                                      \
    asm volatile("s_waitcnt vmcnt(0)" ::: "memory");                                        \
    __builtin_amdgcn_s_barrier();                                                           \
    if ((kt) + 1 < NT) {                                                                    \
      if (!allm) {                                                                          \
        _Pragma("unroll") for (int kvg = 0; kvg < 2; ++kvg)                                 \
            MVL[kvg] = *(const int4*)&mrow[((kt) + 1) * 64 + wk * 32 + kvg * 16 + hi * 4];  \
      }                                                                                     \
      STAGE_KV((P) ^ 1, (kt) + 1);                                                          \
    }                                                                                       \
    f16x8 kf[2][2];                                                                         \
    _Pragma("unroll") for (int kvg = 0; kvg < 2; ++kvg) {                                   \
      kf[kvg][0] = *(const f16x8*)(kbase0 + (P) * 16384 + kvg * 2048);                      \
      kf[kvg][1] = *(const f16x8*)(kbase1 + (P) * 16384 + kvg * 2048);                      \
    }                                                                                       \
    f32x4 s[2][2];                                                                          \
    __builtin_amdgcn_s_setprio(1);                                                          \
    _Pragma("unroll") for (int qg = 0; qg < 2; ++qg)                                        \
        _Pragma("unroll") for (int kvg = 0; kvg < 2; ++kvg) {                               \
      f32x4 z = __builtin_amdgcn_mfma_f32_16x16x32_f16(kf[kvg][0], qf[qg][0], zacc, 0, 0, 0);\
      s[qg][kvg] = __builtin_amdgcn_mfma_f32_16x16x32_f16(kf[kvg][1], qf[qg][1], z, 0, 0, 0);\
    }                                                                                       \
    __builtin_amdgcn_s_setprio(0);                                                          \
    f16x8 pf[2];                                                                            \
    _Pragma("unroll") for (int qg = 0; qg < 2; ++qg) {                                      \
      int wpk[2][2];                                                                        \
      _Pragma("unroll") for (int kvg = 0; kvg < 2; ++kvg) {                                 \
        float p0, p1, p2, p3;                                                               \
        if (allm) {                                                                         \
          p0 = __builtin_amdgcn_exp2f(s[qg][kvg][0]);                                       \
          p1 = __builtin_amdgcn_exp2f(s[qg][kvg][1]);                                       \
          p2 = __builtin_amdgcn_exp2f(s[qg][kvg][2]);                                       \
          p3 = __builtin_amdgcn_exp2f(s[qg][kvg][3]);                                       \
        } else {                                                                            \
          p0 = __builtin_amdgcn_exp2f(MVR[kvg].x ? s[qg][kvg][0] : MASKVAL);                \
          p1 = __builtin_amdgcn_exp2f(MVR[kvg].y ? s[qg][kvg][1] : MASKVAL);                \
          p2 = __builtin_amdgcn_exp2f(MVR[kvg].z ? s[qg][kvg][2] : MASKVAL);                \
          p3 = __builtin_amdgcn_exp2f(MVR[kvg].w ? s[qg][kvg][3] : MASKVAL);                \
        }                                                                                   \
        wpk[kvg][0] = __builtin_bit_cast(int, __builtin_amdgcn_cvt_pkrtz(p0, p1));          \
        wpk[kvg][1] = __builtin_bit_cast(int, __builtin_amdgcn_cvt_pkrtz(p2, p3));          \
      }                                                                                     \
      int A0 = wpk[0][0], B0 = wpk[1][0];                                                   \
      int A1 = wpk[0][1], B1 = wpk[1][1];                                                   \
      asm("v_permlane32_swap_b32 %0, %1" : "+v"(A0), "+v"(B0));                             \
      asm("v_permlane16_swap_b32 %0, %1" : "+v"(A0), "+v"(B0));                             \
      asm("v_permlane32_swap_b32 %0, %1" : "+v"(A1), "+v"(B1));                             \
      asm("v_permlane16_swap_b32 %0, %1" : "+v"(A1), "+v"(B1));                             \
      i32x4 cc = {A0, A1, B0, B1};                                                          \
      pf[qg] = __builtin_bit_cast(f16x8, cc);                                               \
    }                                                                                       \
    f16x8 vf[4];                                                                            \
    _Pragma("unroll") for (int df = 0; df < 4; ++df)                                        \
        vf[df] = *(const f16x8*)(vbase + (P) * 16384 + df * 2048);                          \
    __builtin_amdgcn_s_setprio(1);                                                          \
    _Pragma("unroll") for (int qg = 0; qg < 2; ++qg) {                                      \
      _Pragma("unroll") for (int df = 0; df < 4; ++df)                                      \
          oacc[qg][df] = __builtin_amdgcn_mfma_f32_16x16x32_f16(pf[qg], vf[df], oacc[qg][df], 0, 0, 0); \
      lacc[qg] = __builtin_amdgcn_mfma_f32_16x16x32_f16(pf[qg], ones, lacc[qg], 0, 0, 0);   \
    }                                                                                       \
    __builtin_amdgcn_s_setprio(0);                                                          \
  } while (0)

  for (int kt = 0; kt < NT; kt += 2) {
    ATTN_ITER(kt, 0, mvA, mvB);
    ATTN_ITER(kt + 1, 1, mvB, mvA);
  }

  // ---- cross-wave (wk) reduction through the dead staging LDS ----
  __syncthreads();
  if (wk == 1) {
#pragma unroll
    for (int qg = 0; qg < 2; ++qg) {
#pragma unroll
      for (int df = 0; df < 4; ++df)
        *(f32x4*)(ldsb + wq * 8192 + (qg * 4 + df) * 1024 + lane * 16) = oacc[qg][df];
      *(f32x4*)(ldsb + 16384 + (wq * 2 + qg) * 1024 + lane * 16) = lacc[qg];
    }
  }
  __syncthreads();
  if (wk == 0) {
#pragma unroll
    for (int qg = 0; qg < 2; ++qg) {
#pragma unroll
      for (int df = 0; df < 4; ++df)
        oacc[qg][df] += *(const f32x4*)(ldsb + wq * 8192 + (qg * 4 + df) * 1024 + lane * 16);
      lacc[qg] += *(const f32x4*)(ldsb + 16384 + (wq * 2 + qg) * 1024 + lane * 16);
    }
#pragma unroll
    for (int qg = 0; qg < 2; ++qg) {
      f32x4 rinv;
#pragma unroll
      for (int r = 0; r < 4; ++r) rinv[r] = 1.0f / lacc[qg][r];
#pragma unroll
      for (int df = 0; df < 4; ++df)
#pragma unroll
        for (int r = 0; r < 4; ++r) {
          const int l = qr0 + qg * 16 + hi * 4 + r;
          Oa[(((size_t)b * L + l) * H + h) * HD + df * 16 + lr] =
              (f16)(oacc[qg][df][r] * rinv[r]);
        }
    }
  }
}

// ---------------------------------------------------------------------------
extern "C" void kernel_launch(void* const* d_in, const int* in_sizes, int n_in,
                              void* d_out, int out_size, void* d_ws, size_t ws_size,
                              hipStream_t stream) {
  const float* x  = (const float*)d_in[0];
  const int* mask = (const int*)d_in[1];
  const float* Wq = (const float*)d_in[2];
  const float* bq = (const float*)d_in[3];
  const float* Wk = (const float*)d_in[4];
  const float* bk = (const float*)d_in[5];
  const float* Wv = (const float*)d_in[6];
  const float* bv = (const float*)d_in[7];
  const float* Wo = (const float*)d_in[8];
  const float* bo = (const float*)d_in[9];
  float* out = (float*)d_out;

  char* ws = (char*)d_ws;
  const size_t MB = 1u << 20;
  f16* xh  = (f16*)(ws);             // 4096x1024  (8 MB)
  f16* wqh = (f16*)(ws + 8 * MB);    // 1024x1024  (2 MB)
  f16* wkh = (f16*)(ws + 10 * MB);
  f16* wvh = (f16*)(ws + 12 * MB);
  f16* woh = (f16*)(ws + 14 * MB);
  f16* qh  = (f16*)(ws + 16 * MB);   // [2][16][2048][64], pre-scaled by ALPHA
  f16* kh  = (f16*)(ws + 24 * MB);   // [2][16][2048][64]
  f16* vth = (f16*)(ws + 32 * MB);   // [2][16][64][2048]
  f16* oah = (f16*)(ws + 40 * MB);   // [2][2048][16][64] = [4096][1024]

  conv_all<<<4096, 256, 0, stream>>>(x, Wq, Wk, Wv, Wo, xh, wqh, wkh, wvh, woh);

  gemm_qkv<<<768, 256, 0, stream>>>(xh, wqh, wkh, wvh, bq, bk, bv, qh, kh, vth);

  attn4w<<<dim3(1024), 256, 0, stream>>>(qh, kh, vth, mask, oah);

  gemm_o<<<512, 256, 0, stream>>>(oah, woh, bo, out);
}

// Round 17
// 113.387 us; speedup vs baseline: 1.1145x; 1.0325x over previous
//
#include <hip/hip_runtime.h>
#include <hip/hip_bf16.h>

typedef _Float16 f16;
typedef _Float16 f16x8 __attribute__((ext_vector_type(8)));
typedef _Float16 f16x4 __attribute__((ext_vector_type(4)));
typedef float f32x4 __attribute__((ext_vector_type(4)));
typedef int i32x4 __attribute__((ext_vector_type(4)));

#define LDS_LOAD16(gptr, lptr)                                                             \
  __builtin_amdgcn_global_load_lds(                                                        \
      (const __attribute__((address_space(1))) unsigned int*)(gptr),                       \
      (__attribute__((address_space(3))) unsigned int*)(lptr), 16, 0, 0)

// 0.125 (1/sqrt(HD)) * log2(e): folded into Q so QK^T yields log2e-scaled scores
#define ALPHA 0.18033688f
// masked score: reference sets score=1e-9 (log2e domain)
#define MASKVAL 1.44269504e-9f

// ---------------------------------------------------------------------------
// fused fp32 -> fp16 conversion for x + 4 weight matrices
// ---------------------------------------------------------------------------
__global__ __launch_bounds__(256) void conv_all(const float* __restrict__ x,
                                                const float* __restrict__ Wq,
                                                const float* __restrict__ Wk,
                                                const float* __restrict__ Wv,
                                                const float* __restrict__ Wo,
                                                f16* __restrict__ xh, f16* __restrict__ wqh,
                                                f16* __restrict__ wkh, f16* __restrict__ wvh,
                                                f16* __restrict__ woh) {
  int i = blockIdx.x * 256 + threadIdx.x;
  const float* src;
  f16* dst;
  int off;
  if (i < 524288) {
    src = x; dst = xh; off = i;
  } else {
    int j = i - 524288;
    int w = j >> 17;
    off = j & 131071;
    src = (w == 0) ? Wq : (w == 1) ? Wk : (w == 2) ? Wv : Wo;
    dst = (w == 0) ? wqh : (w == 1) ? wkh : (w == 2) ? wvh : woh;
  }
  const float4* s4 = (const float4*)src;
  float4 a = s4[2 * off];
  float4 b = s4[2 * off + 1];
  f16x8 o = {(f16)a.x, (f16)a.y, (f16)a.z, (f16)a.w,
             (f16)b.x, (f16)b.y, (f16)b.z, (f16)b.w};
  *(f16x8*)(dst + (size_t)off * 8) = o;
}

// ---------------------------------------------------------------------------
// Fused QKV projection: z=0 -> Q (scaled by ALPHA), z=1 -> K, z=2 -> V^T.
// 2-phase pipeline, counted vmcnt(4), dbuf LDS, XCD-chunked swizzle.
// Staging via INCREMENTING stream pointers (+32 elems/step; prefetch = +32
// immediate) -- replaces per-tile 64-bit address recompute (~40 VALU -> ~8).
// ---------------------------------------------------------------------------
__global__ __launch_bounds__(256) void gemm_qkv(const f16* __restrict__ A,
                                                const f16* __restrict__ W0,
                                                const f16* __restrict__ W1,
                                                const f16* __restrict__ W2,
                                                const float* __restrict__ b0,
                                                const float* __restrict__ b1,
                                                const float* __restrict__ b2,
                                                f16* __restrict__ qo, f16* __restrict__ ko,
                                                f16* __restrict__ vo) {
  constexpr int K = 1024, BM = 128, BK = 32, NKT = K / BK;
  __shared__ f16 aT[2][BM * BK];
  __shared__ f16 bT[2][BM * BK];
  const int rid = (blockIdx.x & 7) * 96 + (blockIdx.x >> 3);
  const int z = rid >> 8;
  const f16* Bw = (z == 0) ? W0 : (z == 1) ? W1 : W2;
  const float* bias = (z == 0) ? b0 : (z == 1) ? b1 : b2;
  const int tid = threadIdx.x, wid = tid >> 6, lane = tid & 63;
  const int mb = ((rid >> 3) & 31) * BM, nb = (rid & 7) * BM;
  const int wr = wid >> 1, wc = wid & 1;
  const int lr = lane & 15, hi = lane >> 4;

  f32x4 acc[4][4] = {};

  const int r0 = tid >> 2, s0 = tid & 3;
  const int ci1 = 256 + tid, r1 = ci1 >> 2, s1 = ci1 & 3;

  const f16* pA0 = A + (size_t)(mb + r0) * K + s0 * 8;
  const f16* pB0 = Bw + (size_t)(nb + r0) * K + s0 * 8;
  const f16* pA1 = A + (size_t)(mb + r1) * K + s1 * 8;
  const f16* pB1 = Bw + (size_t)(nb + r1) * K + s1 * 8;

  // prologue: stage tile 0
  LDS_LOAD16(pA0, (char*)aT[0] + wid * 1024);
  LDS_LOAD16(pB0, (char*)bT[0] + wid * 1024);
  LDS_LOAD16(pA1, (char*)aT[0] + 4096 + wid * 1024);
  LDS_LOAD16(pB1, (char*)bT[0] + 4096 + wid * 1024);

  for (int kt = 0; kt < NKT; ++kt) {
    const int p = kt & 1;
    if (kt + 1 < NKT) {
      LDS_LOAD16(pA0 + 32, (char*)aT[p ^ 1] + wid * 1024);
      LDS_LOAD16(pB0 + 32, (char*)bT[p ^ 1] + wid * 1024);
      LDS_LOAD16(pA1 + 32, (char*)aT[p ^ 1] + 4096 + wid * 1024);
      LDS_LOAD16(pB1 + 32, (char*)bT[p ^ 1] + 4096 + wid * 1024);
      asm volatile("s_waitcnt vmcnt(4)" ::: "memory");
    } else {
      asm volatile("s_waitcnt vmcnt(0)" ::: "memory");
    }
    __builtin_amdgcn_s_barrier();

    f16x8 af[4], bf[4];
#pragma unroll
    for (int i = 0; i < 4; ++i) af[i] = *(const f16x8*)&aT[p][(wr * 64 + i * 16 + lr) * BK + hi * 8];
#pragma unroll
    for (int j = 0; j < 4; ++j) bf[j] = *(const f16x8*)&bT[p][(wc * 64 + j * 16 + lr) * BK + hi * 8];
    __builtin_amdgcn_s_setprio(1);
#pragma unroll
    for (int i = 0; i < 4; ++i)
#pragma unroll
      for (int j = 0; j < 4; ++j)
        acc[i][j] = __builtin_amdgcn_mfma_f32_16x16x32_f16(af[i], bf[j], acc[i][j], 0, 0, 0);
    __builtin_amdgcn_s_setprio(0);
    __builtin_amdgcn_s_barrier();

    pA0 += 32; pB0 += 32; pA1 += 32; pB1 += 32;
  }

  const float scale = (z == 0) ? ALPHA : 1.0f;
#pragma unroll
  for (int i = 0; i < 4; ++i) {
#pragma unroll
    for (int j = 0; j < 4; ++j) {
      const int row = mb + wr * 64 + i * 16 + hi * 4;
      const int col = nb + wc * 64 + j * 16 + lr;
      const float bv = bias[col];
      const int hh = col >> 6, dd = col & 63;
      if (z == 2) {
        const int bb = row >> 11, l = row & 2047;
        f16x4 v4;
#pragma unroll
        for (int r = 0; r < 4; ++r) v4[r] = (f16)(acc[i][j][r] + bv);
        *(f16x4*)(vo + ((((size_t)bb * 16 + hh) * 64 + dd) * 2048 + l)) = v4;
      } else {
        f16* o = z ? ko : qo;
#pragma unroll
        for (int r = 0; r < 4; ++r) {
          const int m2 = row + r;
          const int bb = m2 >> 11, l = m2 & 2047;
          o[((((size_t)bb * 16 + hh) * 2048 + l) * 64) + dd] = (f16)((acc[i][j][r] + bv) * scale);
        }
      }
    }
  }
}

// ---------------------------------------------------------------------------
// Output projection: 64(M)x128(N) tile, 2-phase pipeline, XCD-chunked swizzle,
// incrementing stream pointers.
// ---------------------------------------------------------------------------
__global__ __launch_bounds__(256) void gemm_o(const f16* __restrict__ A,
                                              const f16* __restrict__ W,
                                              const float* __restrict__ bias,
                                              float* __restrict__ out) {
  constexpr int K = 1024, N = 1024, BK = 32, NKT = K / BK;
  __shared__ f16 aT[2][64 * BK];
  __shared__ f16 bT[2][128 * BK];
  const int rid = (blockIdx.x & 7) * 64 + (blockIdx.x >> 3);
  const int tid = threadIdx.x, wid = tid >> 6, lane = tid & 63;
  const int lr = lane & 15, hi = lane >> 4;
  const int mb = (rid >> 3) * 64, nb = (rid & 7) * 128;
  const int wr = wid >> 1, wc = wid & 1;
  f32x4 acc[2][4] = {};
  const int ra = tid >> 2, sa = tid & 3;
  const int rb1 = (256 + tid) >> 2, sb1 = (256 + tid) & 3;

  const f16* pA = A + (size_t)(mb + ra) * K + sa * 8;
  const f16* pB0 = W + (size_t)(nb + ra) * K + sa * 8;
  const f16* pB1 = W + (size_t)(nb + rb1) * K + sb1 * 8;

  LDS_LOAD16(pA, (char*)aT[0] + wid * 1024);
  LDS_LOAD16(pB0, (char*)bT[0] + wid * 1024);
  LDS_LOAD16(pB1, (char*)bT[0] + 4096 + wid * 1024);

  for (int kt = 0; kt < NKT; ++kt) {
    const int p = kt & 1;
    if (kt + 1 < NKT) {
      LDS_LOAD16(pA + 32, (char*)aT[p ^ 1] + wid * 1024);
      LDS_LOAD16(pB0 + 32, (char*)bT[p ^ 1] + wid * 1024);
      LDS_LOAD16(pB1 + 32, (char*)bT[p ^ 1] + 4096 + wid * 1024);
      asm volatile("s_waitcnt vmcnt(3)" ::: "memory");
    } else {
      asm volatile("s_waitcnt vmcnt(0)" ::: "memory");
    }
    __builtin_amdgcn_s_barrier();
    f16x8 af[2], bf[4];
#pragma unroll
    for (int i = 0; i < 2; ++i) af[i] = *(const f16x8*)&aT[p][(wr * 32 + i * 16 + lr) * BK + hi * 8];
#pragma unroll
    for (int j = 0; j < 4; ++j) bf[j] = *(const f16x8*)&bT[p][(wc * 64 + j * 16 + lr) * BK + hi * 8];
    __builtin_amdgcn_s_setprio(1);
#pragma unroll
    for (int i = 0; i < 2; ++i)
#pragma unroll
      for (int j = 0; j < 4; ++j)
        acc[i][j] = __builtin_amdgcn_mfma_f32_16x16x32_f16(af[i], bf[j], acc[i][j], 0, 0, 0);
    __builtin_amdgcn_s_setprio(0);
    __builtin_amdgcn_s_barrier();

    pA += 32; pB0 += 32; pB1 += 32;
  }
#pragma unroll
  for (int i = 0; i < 2; ++i)
#pragma unroll
    for (int j = 0; j < 4; ++j) {
      const int col = nb + wc * 64 + j * 16 + lr;
      const float bv = bias[col];
#pragma unroll
      for (int r = 0; r < 4; ++r)
        out[(size_t)(mb + wr * 32 + i * 16 + hi * 4 + r) * N + col] = acc[i][j][r] + bv;
    }
}

// ---------------------------------------------------------------------------
// Flash attention v8.1 (kv-split hybrid + incrementing stage pointers):
// 4 waves = 2(kv-half) x 2(q-half); wave (wk,wq) computes PARTIAL O for its
// q rows over its kv slice; partials reduced once at end through dead LDS.
// Staging addresses via 6 stream pointers advanced by constants per 2-tile
// outer iter (K: +8192 elems, V: +128 elems) -- no per-tile addr recompute.
// In-register P transpose (permlane32+16), ones-MFMA row-sums, mask all-ones
// fast path, p = exp2(score*log2e) (Q pre-scaled by ALPHA).
// ---------------------------------------------------------------------------
__global__ __launch_bounds__(256, 4) void attn4w(const f16* __restrict__ Qh,
                                                 const f16* __restrict__ Kh,
                                                 const f16* __restrict__ Vt,
                                                 const int* __restrict__ mask,
                                                 f16* __restrict__ Oa) {
  constexpr int L = 2048, HD = 64, H = 16, NT = L / 64;
  __shared__ __align__(16) char ldsb[32768];

  const int tid = threadIdx.x, wid = tid >> 6, lane = tid & 63;
  const int wk = wid >> 1, wq = wid & 1;
  const int lr = lane & 15, hi = lane >> 4;
  const int sw = lr & 7;

  const int bid = blockIdx.x;  // 1024 blocks
  const int head = (bid & 7) * 4 + (bid >> 8);
  const int qb = (bid >> 3) & 31;
  const int b = head >> 4, h = head & 15;
  const int qr0 = qb * 64 + wq * 32;

  const f16* Qb = Qh + (size_t)head * L * HD;
  const f16* Kb = Kh + (size_t)head * L * HD;
  const f16* Vb = Vt + (size_t)head * HD * L;
  const int* mrow = mask + b * L;

  int mred = 1;
  {
    const int4* m4 = (const int4*)mrow;
#pragma unroll
    for (int j = 0; j < 8; ++j) {
      int4 v = m4[lane + j * 64];
      mred &= v.x & v.y & v.z & v.w;
    }
  }
  const bool allm = __all(mred == 1);

  const int srow = lane >> 3;
  const int schk = (lane & 7) ^ srow;

  // stream pointers: kSo/vSo* stage ODD tiles (1,3,..); kSe/vSe* stage EVEN
  // tiles (2,4,..).  Advanced by 2-tile strides at the bottom of the loop.
  const f16* kSo = Kb + (size_t)(64 + wid * 16 + srow) * HD + schk * 8;
  const f16* kSe = Kb + (size_t)(128 + wid * 16 + srow) * HD + schk * 8;
  const f16* vSo0 = Vb + (size_t)(wid * 16 + srow) * L + 64 + schk * 8;
  const f16* vSo1 = Vb + (size_t)(wid * 16 + 8 + srow) * L + 64 + schk * 8;
  const f16* vSe0 = Vb + (size_t)(wid * 16 + srow) * L + 128 + schk * 8;
  const f16* vSe1 = Vb + (size_t)(wid * 16 + 8 + srow) * L + 128 + schk * 8;

  const char* kbase0 = ldsb + (wk * 32 + lr) * 128 + ((hi ^ sw) * 16);
  const char* kbase1 = ldsb + (wk * 32 + lr) * 128 + (((4 + hi) ^ sw) * 16);
  const char* vbase = ldsb + 8192 + lr * 128 + (((wk * 4 + hi) ^ sw) * 16);

  f16x8 qf[2][2];
#pragma unroll
  for (int qg = 0; qg < 2; ++qg)
#pragma unroll
    for (int k2 = 0; k2 < 2; ++k2)
      qf[qg][k2] = *(const f16x8*)&Qb[(size_t)(qr0 + qg * 16 + lr) * HD + k2 * 32 + hi * 8];

  f32x4 oacc[2][4] = {};
  f32x4 lacc[2] = {};
  const f32x4 zacc = {0.f, 0.f, 0.f, 0.f};
  const f16x8 ones = {1, 1, 1, 1, 1, 1, 1, 1};

  int4 mvA[2], mvB[2];
  if (!allm) {
#pragma unroll
    for (int kvg = 0; kvg < 2; ++kvg)
      mvA[kvg] = *(const int4*)&mrow[wk * 32 + kvg * 16 + hi * 4];
  }

  // prologue: stage tile 0
  LDS_LOAD16(Kb + (size_t)(wid * 16 + srow) * HD + schk * 8, ldsb + wid * 2048);
  LDS_LOAD16(Kb + (size_t)(wid * 16 + 8 + srow) * HD + schk * 8, ldsb + wid * 2048 + 1024);
  LDS_LOAD16(Vb + (size_t)(wid * 16 + srow) * L + schk * 8, ldsb + 8192 + wid * 2048);
  LDS_LOAD16(Vb + (size_t)(wid * 16 + 8 + srow) * L + schk * 8, ldsb + 8192 + wid * 2048 + 1024);

#define ATTN_ITER(kt, P, MVR, MVL, KP, V0, V1)                                              \
  do {                                                                                      \
    asm volatile("s_waitcnt vmcnt(0)" ::: "memory");                                        \
    __builtin_amdgcn_s_barrier();                                                           \
    if ((kt) + 1 < NT) {                                                                    \
      if (!allm) {                                                                          \
        _Pragma("unroll") for (int kvg = 0; kvg < 2; ++kvg)                                 \
            MVL[kvg] = *(const int4*)&mrow[((kt) + 1) * 64 + wk * 32 + kvg * 16 + hi * 4];  \
      }                                                                                     \
      LDS_LOAD16(KP, ldsb + ((P) ^ 1) * 16384 + wid * 2048);                                \
      LDS_LOAD16(KP + 512, ldsb + ((P) ^ 1) * 16384 + wid * 2048 + 1024);                   \
      LDS_LOAD16(V0, ldsb + ((P) ^ 1) * 16384 + 8192 + wid * 2048);                         \
      LDS_LOAD16(V1, ldsb + ((P) ^ 1) * 16384 + 8192 + wid * 2048 + 1024);                  \
    }                                                                                       \
    f16x8 kf[2][2];                                                                         \
    _Pragma("unroll") for (int kvg = 0; kvg < 2; ++kvg) {                                   \
      kf[kvg][0] = *(const f16x8*)(kbase0 + (P) * 16384 + kvg * 2048);                      \
      kf[kvg][1] = *(const f16x8*)(kbase1 + (P) * 16384 + kvg * 2048);                      \
    }                                                                                       \
    f32x4 s[2][2];                                                                          \
    __builtin_amdgcn_s_setprio(1);                                                          \
    _Pragma("unroll") for (int qg = 0; qg < 2; ++qg)                                        \
        _Pragma("unroll") for (int kvg = 0; kvg < 2; ++kvg) {                               \
      f32x4 z = __builtin_amdgcn_mfma_f32_16x16x32_f16(kf[kvg][0], qf[qg][0], zacc, 0, 0, 0);\
      s[qg][kvg] = __builtin_amdgcn_mfma_f32_16x16x32_f16(kf[kvg][1], qf[qg][1], z, 0, 0, 0);\
    }                                                                                       \
    __builtin_amdgcn_s_setprio(0);                                                          \
    f16x8 pf[2];                                                                            \
    _Pragma("unroll") for (int qg = 0; qg < 2; ++qg) {                                      \
      int wpk[2][2];                                                                        \
      _Pragma("unroll") for (int kvg = 0; kvg < 2; ++kvg) {                                 \
        float p0, p1, p2, p3;                                                               \
        if (allm) {                                                                         \
          p0 = __builtin_amdgcn_exp2f(s[qg][kvg][0]);                                       \
          p1 = __builtin_amdgcn_exp2f(s[qg][kvg][1]);                                       \
          p2 = __builtin_amdgcn_exp2f(s[qg][kvg][2]);                                       \
          p3 = __builtin_amdgcn_exp2f(s[qg][kvg][3]);                                       \
        } else {                                                                            \
          p0 = __builtin_amdgcn_exp2f(MVR[kvg].x ? s[qg][kvg][0] : MASKVAL);                \
          p1 = __builtin_amdgcn_exp2f(MVR[kvg].y ? s[qg][kvg][1] : MASKVAL);                \
          p2 = __builtin_amdgcn_exp2f(MVR[kvg].z ? s[qg][kvg][2] : MASKVAL);                \
          p3 = __builtin_amdgcn_exp2f(MVR[kvg].w ? s[qg][kvg][3] : MASKVAL);                \
        }                                                                                   \
        wpk[kvg][0] = __builtin_bit_cast(int, __builtin_amdgcn_cvt_pkrtz(p0, p1));          \
        wpk[kvg][1] = __builtin_bit_cast(int, __builtin_amdgcn_cvt_pkrtz(p2, p3));          \
      }                                                                                     \
      int A0 = wpk[0][0], B0 = wpk[1][0];                                                   \
      int A1 = wpk[0][1], B1 = wpk[1][1];                                                   \
      asm("v_permlane32_swap_b32 %0, %1" : "+v"(A0), "+v"(B0));                             \
      asm("v_permlane16_swap_b32 %0, %1" : "+v"(A0), "+v"(B0));                             \
      asm("v_permlane32_swap_b32 %0, %1" : "+v"(A1), "+v"(B1));                             \
      asm("v_permlane16_swap_b32 %0, %1" : "+v"(A1), "+v"(B1));                             \
      i32x4 cc = {A0, A1, B0, B1};                                                          \
      pf[qg] = __builtin_bit_cast(f16x8, cc);                                               \
    }                                                                                       \
    f16x8 vf[4];                                                                            \
    _Pragma("unroll") for (int df = 0; df < 4; ++df)                                        \
        vf[df] = *(const f16x8*)(vbase + (P) * 16384 + df * 2048);                          \
    __builtin_amdgcn_s_setprio(1);                                                          \
    _Pragma("unroll") for (int qg = 0; qg < 2; ++qg) {                                      \
      _Pragma("unroll") for (int df = 0; df < 4; ++df)                                      \
          oacc[qg][df] = __builtin_amdgcn_mfma_f32_16x16x32_f16(pf[qg], vf[df], oacc[qg][df], 0, 0, 0); \
      lacc[qg] = __builtin_amdgcn_mfma_f32_16x16x32_f16(pf[qg], ones, lacc[qg], 0, 0, 0);   \
    }                                                                                       \
    __builtin_amdgcn_s_setprio(0);                                                          \
  } while (0)

  for (int kt = 0; kt < NT; kt += 2) {
    ATTN_ITER(kt, 0, mvA, mvB, kSo, vSo0, vSo1);
    ATTN_ITER(kt + 1, 1, mvB, mvA, kSe, vSe0, vSe1);
    kSo += 8192; kSe += 8192;
    vSo0 += 128; vSo1 += 128; vSe0 += 128; vSe1 += 128;
  }

  // ---- cross-wave (wk) reduction through the dead staging LDS ----
  __syncthreads();
  if (wk == 1) {
#pragma unroll
    for (int qg = 0; qg < 2; ++qg) {
#pragma unroll
      for (int df = 0; df < 4; ++df)
        *(f32x4*)(ldsb + wq * 8192 + (qg * 4 + df) * 1024 + lane * 16) = oacc[qg][df];
      *(f32x4*)(ldsb + 16384 + (wq * 2 + qg) * 1024 + lane * 16) = lacc[qg];
    }
  }
  __syncthreads();
  if (wk == 0) {
#pragma unroll
    for (int qg = 0; qg < 2; ++qg) {
#pragma unroll
      for (int df = 0; df < 4; ++df)
        oacc[qg][df] += *(const f32x4*)(ldsb + wq * 8192 + (qg * 4 + df) * 1024 + lane * 16);
      lacc[qg] += *(const f32x4*)(ldsb + 16384 + (wq * 2 + qg) * 1024 + lane * 16);
    }
#pragma unroll
    for (int qg = 0; qg < 2; ++qg) {
      f32x4 rinv;
#pragma unroll
      for (int r = 0; r < 4; ++r) rinv[r] = 1.0f / lacc[qg][r];
#pragma unroll
      for (int df = 0; df < 4; ++df)
#pragma unroll
        for (int r = 0; r < 4; ++r) {
          const int l = qr0 + qg * 16 + hi * 4 + r;
          Oa[(((size_t)b * L + l) * H + h) * HD + df * 16 + lr] =
              (f16)(oacc[qg][df][r] * rinv[r]);
        }
    }
  }
}

// ---------------------------------------------------------------------------
extern "C" void kernel_launch(void* const* d_in, const int* in_sizes, int n_in,
                              void* d_out, int out_size, void* d_ws, size_t ws_size,
                              hipStream_t stream) {
  const float* x  = (const float*)d_in[0];
  const int* mask = (const int*)d_in[1];
  const float* Wq = (const float*)d_in[2];
  const float* bq = (const float*)d_in[3];
  const float* Wk = (const float*)d_in[4];
  const float* bk = (const float*)d_in[5];
  const float* Wv = (const float*)d_in[6];
  const float* bv = (const float*)d_in[7];
  const float* Wo = (const float*)d_in[8];
  const float* bo = (const float*)d_in[9];
  float* out = (float*)d_out;

  char* ws = (char*)d_ws;
  const size_t MB = 1u << 20;
  f16* xh  = (f16*)(ws);             // 4096x1024  (8 MB)
  f16* wqh = (f16*)(ws + 8 * MB);    // 1024x1024  (2 MB)
  f16* wkh = (f16*)(ws + 10 * MB);
  f16* wvh = (f16*)(ws + 12 * MB);
  f16* woh = (f16*)(ws + 14 * MB);
  f16* qh  = (f16*)(ws + 16 * MB);   // [2][16][2048][64], pre-scaled by ALPHA
  f16* kh  = (f16*)(ws + 24 * MB);   // [2][16][2048][64]
  f16* vth = (f16*)(ws + 32 * MB);   // [2][16][64][2048]
  f16* oah = (f16*)(ws + 40 * MB);   // [2][2048][16][64] = [4096][1024]

  conv_all<<<4096, 256, 0, stream>>>(x, Wq, Wk, Wv, Wo, xh, wqh, wkh, wvh, woh);

  gemm_qkv<<<768, 256, 0, stream>>>(xh, wqh, wkh, wvh, bq, bk, bv, qh, kh, vth);

  attn4w<<<dim3(1024), 256, 0, stream>>>(qh, kh, vth, mask, oah);

  gemm_o<<<512, 256, 0, stream>>>(oah, woh, bo, out);
}